// Round 1
// 94.398 us; speedup vs baseline: 1.3085x; 1.3085x over previous
//
#include <hip/hip_runtime.h>
#include <hip/hip_bf16.h>
#include <math.h>

// MultiSimilarityLoss on MI355X.
// x: [n,128] fp32 L2-normalized; t: [n] int32 labels; out: 4 fp32
// (loss, prec, mean_pos_sim(last row), mean_neg_sim(last row)).
// ep = EPOCH_NUM/300 = 1.0, BASE=0.5, POS_MARGIN=0.9, NEG_MARGIN=0.1.
//
// R16: R15 + pos path moved from scalar-VALU dots (2048 sub-blocks,
// ~half the fused kernel's VALU cycles) to MFMA group tiles (128 blocks,
// one per label). Gather rows via list[] with per-lane global src into
// the same swizzled global_load_lds staging as the neg path; identical
// 128x128x128 bf16 MFMA; epilogue extracts per-row min / sum(exp) with
// (col<m & s<0.9) mask through the LDS-partial reduction. prep_kernel
// bumped to 1024-thread blocks (4x shorter serial bucketing).
// exp args expanded: neg 50(s-.5)+(.1-s)^2 = s^2+49.8s-24.99
//                    pos -2(s-.5)+(s-.9)^2 = s^2-3.8s+1.81

#define D 128
#define NL 128   // labels are 0..99; padded
#define POSB NL  // pos blocks: one per label group

typedef __attribute__((ext_vector_type(8))) short short8;
typedef __attribute__((ext_vector_type(4))) float float4v;

// ---------------- wave reduce helpers ----------------
__device__ inline float waveSum(float v) {
    #pragma unroll
    for (int o = 32; o > 0; o >>= 1) v += __shfl_down(v, o, 64);
    return v;
}
__device__ inline float waveMin(float v) {
    #pragma unroll
    for (int o = 32; o > 0; o >>= 1) v = fminf(v, __shfl_down(v, o, 64));
    return v;
}

// async 16B global->LDS (LDS dst: wave-uniform base + lane*16)
__device__ inline void load_lds16(const void* g, void* l) {
    __builtin_amdgcn_global_load_lds(
        (const __attribute__((address_space(1))) unsigned int*)g,
        (__attribute__((address_space(3))) unsigned int*)l, 16, 0, 0);
}

// ---------------- kernel A: convert + bucket + zero workspace ---------------
__global__ __launch_bounds__(1024) void prep_kernel(
    const float* __restrict__ x, ushort* __restrict__ xb, int total8,
    const int* __restrict__ t, int* __restrict__ offs, int* __restrict__ list,
    float* __restrict__ part, float* __restrict__ last4,
    float* __restrict__ out, int n, int nconv)
{
    const int tid = threadIdx.x;
    const int bx = blockIdx.x;
    if (bx < nconv) {
        const int g = bx * 1024 + tid;
        if (g >= total8) return;
        const float4* src = (const float4*)(x) + g * 2;
        float4 a = src[0], b = src[1];
        float f[8] = {a.x, a.y, a.z, a.w, b.x, b.y, b.z, b.w};
        ushort r[8];
        #pragma unroll
        for (int i = 0; i < 8; ++i) {
            unsigned u = __float_as_uint(f[i]);
            r[i] = (ushort)((u + 0x7FFFu + ((u >> 16) & 1u)) >> 16);   // RNE
        }
        uint4 packed;
        packed.x = (unsigned)r[0] | ((unsigned)r[1] << 16);
        packed.y = (unsigned)r[2] | ((unsigned)r[3] << 16);
        packed.z = (unsigned)r[4] | ((unsigned)r[5] << 16);
        packed.w = (unsigned)r[6] | ((unsigned)r[7] << 16);
        ((uint4*)xb)[g] = packed;
        return;
    }
    if (bx > nconv) {   // zero part
        const int zb = bx - nconv - 1;
        const int g4 = zb * 4096 + tid * 4;
        if (g4 < 8 * n)
            *(float4*)(part + g4) = (float4){0.f, 0.f, 0.f, 0.f};
        return;
    }
    // bucketing block (also zeroes last4 and out accumulators)
    __shared__ int cnt[NL], cur[NL];
    if (tid < 4) { last4[tid] = 0.f; out[tid] = 0.f; }
    if (tid < NL) cnt[tid] = 0;
    __syncthreads();
    for (int j = tid; j < n; j += 1024) atomicAdd(&cnt[t[j]], 1);
    __syncthreads();
    if (tid == 0) {
        int acc = 0;
        for (int g = 0; g < NL; ++g) { cur[g] = acc; offs[g] = acc; acc += cnt[g]; }
        offs[NL] = acc;
    }
    __syncthreads();
    for (int j = tid; j < n; j += 1024) {
        int p = atomicAdd(&cur[t[j]], 1);
        list[p] = j;
    }
}

// ---------------- kernel B: FUSED MFMA pos groups + triangular MFMA neg ----
// blocks [0,POSB): pos label groups. blocks [POSB,POSB+ntri): neg tiles.
__global__ __launch_bounds__(256, 3) void fused_kernel(
    const ushort* __restrict__ xb,
    const int* __restrict__ t,
    const int* __restrict__ offs, const int* __restrict__ list,
    float* __restrict__ pos_min, float* __restrict__ pos_sum,
    float* __restrict__ part, float* __restrict__ last4, int n, int ntri)
{
    __shared__ __align__(16) unsigned char smem[32768 + 2048];
    const int tid = threadIdx.x;
    const int bx = blockIdx.x;

    const int w = tid >> 6, lane = tid & 63;
    const int wy = w >> 1, wx = w & 1;
    const int quad = lane >> 4, lq = lane & 15;

    if (bx >= POSB) {
        // ================= NEG tile path =================
        int b = bx - POSB;
        int r = (int)((sqrtf(8.0f * (float)b + 1.0f) - 1.0f) * 0.5f);
        while ((r + 1) * (r + 2) / 2 <= b) ++r;
        while (r * (r + 1) / 2 > b) --r;
        const int c = b - r * (r + 1) / 2;
        const bool offdiag = (r != c);

        const int i0 = r * 128, j0 = c * 128;
        const bool has_last = (i0 == n - 128);

        int* labr = (int*)(smem + 32768);
        int* labc = labr + 128;
        for (int l = tid; l < 128; l += 256) {
            labr[l] = t[i0 + l];
            labc[l] = t[j0 + l];
        }

        uint4* Au = (uint4*)smem;               // [128][8] chunks, swizzled
        uint4* Bu = Au + 128 * 8;
        const uint4* xbv = (const uint4*)xb;
        const short8* As = (const short8*)Au;
        const short8* Bs = (const short8*)Bu;

        float4v acc[4][4];
        #pragma unroll
        for (int a = 0; a < 4; ++a)
            #pragma unroll
            for (int d2 = 0; d2 < 4; ++d2) acc[a][d2] = (float4v){0.f, 0.f, 0.f, 0.f};

        #pragma unroll
        for (int h = 0; h < 2; ++h) {           // K half: cols [h*64, h*64+64)
            if (h) __syncthreads();             // done reading previous half
            // async stage: dst slot d = tid + it*256; LDS dst is uniform
            // base (it*256 + wave*64)*16 + lane*16; swizzle on global side.
            #pragma unroll
            for (int it = 0; it < 4; ++it) {
                const int d = tid + it * 256;   // 0..1023
                const int row = d >> 3;
                const int q = (d & 7) ^ (row & 7);
                const int ub = (d & ~63) * 16;  // wave-uniform byte offset
                load_lds16(xbv + (size_t)(i0 + row) * 16 + h * 8 + q,
                           (char*)Au + ub);
                load_lds16(xbv + (size_t)(j0 + row) * 16 + h * 8 + q,
                           (char*)Bu + ub);
            }
            __syncthreads();                    // drains vmcnt (loads landed)
            #pragma unroll
            for (int s = 0; s < 2; ++s) {       // k = h*64 + s*32 + quad*8 + j
                short8 af[4], bf[4];
                #pragma unroll
                for (int tt = 0; tt < 4; ++tt) {
                    const int ra = wy * 64 + tt * 16 + lq;
                    const int rb2 = wx * 64 + tt * 16 + lq;
                    af[tt] = As[ra * 8 + ((s * 4 + quad) ^ (lq & 7))];
                    bf[tt] = Bs[rb2 * 8 + ((s * 4 + quad) ^ (lq & 7))];
                }
                #pragma unroll
                for (int tr = 0; tr < 4; ++tr)
                    #pragma unroll
                    for (int tc = 0; tc < 4; ++tc)
                        acc[tr][tc] = __builtin_amdgcn_mfma_f32_16x16x32_bf16(
                            af[tr], bf[tc], acc[tr][tc], 0, 0, 0);
            }
        }
        __syncthreads();     // all waves done reading A/B before aliasing

        float* pp_r = (float*)smem;             // [32][129] row partials
        float* pp_c = ((float*)smem) + 32 * 129;   // [8][129] col partials

        int lcv[4];
        #pragma unroll
        for (int tc = 0; tc < 4; ++tc) lcv[tc] = labc[wx * 64 + tc * 16 + lq];
        float colp[4] = {0.f, 0.f, 0.f, 0.f};

        #pragma unroll
        for (int tr = 0; tr < 4; ++tr) {
            #pragma unroll
            for (int reg = 0; reg < 4; ++reg) {
                const int row_loc = wy * 64 + tr * 16 + quad * 4 + reg;
                const int lr = labr[row_loc];
                float ns = 0.f;
                #pragma unroll
                for (int tc = 0; tc < 4; ++tc) {
                    const float s = acc[tr][tc][reg];
                    const bool sel = (lr != lcv[tc]) & (s > 0.1f);
                    const float e = sel
                        ? __expf(fmaf(s, s, fmaf(49.8f, s, -24.99f))) : 0.f;
                    ns += e; colp[tc] += e;
                }
                pp_r[(wx * 16 + lq) * 129 + row_loc] = ns;

                if (has_last && (i0 + row_loc == n - 1)) {  // last-row stats (pth=0.1)
                    float ssim = 0.f, ncf = 0.f;
                    #pragma unroll
                    for (int tc = 0; tc < 4; ++tc) {
                        const float s = acc[tr][tc][reg];
                        if ((lr != lcv[tc]) & (s > 0.1f)) { ssim += s; ncf += 1.f; }
                    }
                    #pragma unroll
                    for (int o = 1; o < 16; o <<= 1) {
                        ssim += __shfl_xor(ssim, o, 64);
                        ncf  += __shfl_xor(ncf, o, 64);
                    }
                    if (lq == 0 && ncf > 0.f) {
                        atomicAdd(&last4[2], ssim);
                        atomicAdd(&last4[3], ncf);
                    }
                }
            }
        }
        if (offdiag) {
            #pragma unroll
            for (int tc = 0; tc < 4; ++tc)
                pp_c[(wy * 4 + quad) * 129 + (wx * 64 + tc * 16 + lq)] = colp[tc];
        }
        __syncthreads();

        if (tid < 128) {
            float s = 0.f;
            #pragma unroll
            for (int cc = 0; cc < 32; ++cc) s += pp_r[cc * 129 + tid];
            atomicAdd(&part[(size_t)(c & 7) * n + i0 + tid], s);  // <=8 writers/slice
            if (offdiag) {
                float s2 = 0.f;
                #pragma unroll
                for (int cc = 0; cc < 8; ++cc) s2 += pp_c[cc * 129 + tid];
                atomicAdd(&part[(size_t)(r & 7) * n + j0 + tid], s2);
            }
        }
        return;
    }

    // ================= POS group path (MFMA, one block per label) ==========
    const int g = bx;
    const int s0 = offs[g], m = offs[g + 1] - s0;
    if (m <= 0) return;

    uint4* Au = (uint4*)smem;               // [128][8] chunks, swizzled
    uint4* Bu = Au + 128 * 8;
    const uint4* xbv = (const uint4*)xb;
    const short8* As = (const short8*)Au;
    const short8* Bs = (const short8*)Bu;
    int* lrow = (int*)(smem + 33280);       // [128] gathered row ids
    int* lcol = lrow + 128;                 // [128] gathered col ids
    // pp arrays alias [0,33024) AFTER the MFMA reads are barrier-drained;
    // lrow/lcol live at 33280 so they survive the aliasing.

    const int lastlab = t[n - 1];
    const bool glast = (g == lastlab);
    const int nrt = (m + 127) >> 7;

    for (int rt = 0; rt < nrt; ++rt) {
        const int rbase = rt << 7;
        const int rleft = min(128, m - rbase);
        for (int ct = 0; ct < nrt; ++ct) {
            const int cbase = ct << 7;
            __syncthreads();                // prior pp/lrow readers done
            for (int l = tid; l < 128; l += 256) {
                lrow[l] = list[s0 + min(rbase + l, m - 1)];
                lcol[l] = list[s0 + min(cbase + l, m - 1)];
            }
            __syncthreads();

            float4v acc[4][4];
            #pragma unroll
            for (int a = 0; a < 4; ++a)
                #pragma unroll
                for (int d2 = 0; d2 < 4; ++d2) acc[a][d2] = (float4v){0.f, 0.f, 0.f, 0.f};

            #pragma unroll
            for (int h = 0; h < 2; ++h) {
                if (h) __syncthreads();
                #pragma unroll
                for (int it = 0; it < 4; ++it) {
                    const int d = tid + it * 256;
                    const int row = d >> 3;
                    const int q = (d & 7) ^ (row & 7);
                    const int ub = (d & ~63) * 16;
                    load_lds16(xbv + (size_t)lrow[row] * 16 + h * 8 + q,
                               (char*)Au + ub);
                    load_lds16(xbv + (size_t)lcol[row] * 16 + h * 8 + q,
                               (char*)Bu + ub);
                }
                __syncthreads();
                #pragma unroll
                for (int ks = 0; ks < 2; ++ks) {
                    short8 af[4], bf[4];
                    #pragma unroll
                    for (int tt = 0; tt < 4; ++tt) {
                        const int ra = wy * 64 + tt * 16 + lq;
                        const int rb2 = wx * 64 + tt * 16 + lq;
                        af[tt] = As[ra * 8 + ((ks * 4 + quad) ^ (lq & 7))];
                        bf[tt] = Bs[rb2 * 8 + ((ks * 4 + quad) ^ (lq & 7))];
                    }
                    #pragma unroll
                    for (int tr = 0; tr < 4; ++tr)
                        #pragma unroll
                        for (int tc = 0; tc < 4; ++tc)
                            acc[tr][tc] = __builtin_amdgcn_mfma_f32_16x16x32_bf16(
                                af[tr], bf[tc], acc[tr][tc], 0, 0, 0);
                }
            }
            __syncthreads();     // staging reads done -> alias as partials

            float* pp_s = (float*)smem;                 // [32][129] sum partials
            float* pp_m = ((float*)smem) + 32 * 129;    // [32][129] min partials
            float ssl = 0.f, scl = 0.f;
            bool hadlast = false;

            #pragma unroll
            for (int tr = 0; tr < 4; ++tr) {
                #pragma unroll
                for (int reg = 0; reg < 4; ++reg) {
                    const int row_loc = wy * 64 + tr * 16 + quad * 4 + reg;
                    float ps = 0.f, mn = INFINITY;
                    #pragma unroll
                    for (int tc = 0; tc < 4; ++tc) {
                        const int col = cbase + wx * 64 + tc * 16 + lq;
                        const float sv = acc[tr][tc][reg];
                        const bool val = (col < m) & (sv < 0.9f);  // excl. self (sv~1)
                        mn = fminf(mn, val ? sv : INFINITY);
                        ps += val ? __expf(fmaf(sv, sv, fmaf(-3.8f, sv, 1.81f))) : 0.f;
                    }
                    pp_s[(wx * 16 + lq) * 129 + row_loc] = ps;
                    pp_m[(wx * 16 + lq) * 129 + row_loc] = mn;

                    if (glast && row_loc < rleft && lrow[row_loc] == n - 1) {
                        hadlast = true;
                        #pragma unroll
                        for (int tc = 0; tc < 4; ++tc) {
                            const int col = cbase + wx * 64 + tc * 16 + lq;
                            const float sv = acc[tr][tc][reg];
                            if ((col < m) & (sv < 0.9f)) { ssl += sv; scl += 1.f; }
                        }
                    }
                }
            }
            if (glast) {
                #pragma unroll
                for (int o = 1; o < 16; o <<= 1) {
                    ssl += __shfl_xor(ssl, o, 64);
                    scl += __shfl_xor(scl, o, 64);
                }
                if (hadlast && lq == 0) {
                    atomicAdd(&last4[0], ssl);
                    atomicAdd(&last4[1], scl);
                }
            }
            __syncthreads();

            if (tid < rleft) {
                float sres = 0.f, mres = INFINITY;
                #pragma unroll
                for (int cc = 0; cc < 32; ++cc) {
                    sres += pp_s[cc * 129 + tid];
                    mres = fminf(mres, pp_m[cc * 129 + tid]);
                }
                const int i = lrow[tid];
                if (ct == 0) { pos_sum[i] = sres; pos_min[i] = mres; }
                else {
                    pos_sum[i] += sres;
                    pos_min[i] = fminf(pos_min[i], mres);
                }
            }
        }
    }
}

// ---------------- kernel C: finalize (32 blocks) + exact-path cleanup ------
__global__ __launch_bounds__(256) void finalize_kernel(
    const ushort* __restrict__ xb, const int* __restrict__ t,
    const float* __restrict__ pos_min, const float* __restrict__ pos_sum,
    const float* __restrict__ part, const float* __restrict__ last4,
    float* __restrict__ out, int n)
{
    const int tid = threadIdx.x;
    const int base = blockIdx.x * 256;
    const int i = base + tid;
    const float pm = pos_min[i];
    const bool flag = (pm > 0.6f);   // pth would exceed 0.1 (incl. pm=+inf)

    __shared__ int fl[256];
    __shared__ int nfl, lastflag;
    __shared__ float corr[256];
    __shared__ float xi2[D];
    __shared__ float red[3][4];
    __shared__ float lastst[2];
    if (tid == 0) { nfl = 0; lastflag = 0; }
    __syncthreads();
    if (flag) { int q = atomicAdd(&nfl, 1); fl[q] = tid; }
    __syncthreads();
    const int m = nfl;

    for (int e = 0; e < m; ++e) {    // rare: exact recompute of flagged rows
        const int lr_ = fl[e];
        const int ri = base + lr_;
        if (tid < D)
            xi2[tid] = __uint_as_float(((unsigned)xb[(size_t)ri * D + tid]) << 16);
        __syncthreads();
        const float pth = fmaxf(0.1f, pos_min[ri] - 0.5f);
        const int lab = t[ri];
        float S = 0.f, ss = 0.f, cnt = 0.f;
        for (int j = tid; j < n; j += 256) {
            if (t[j] == lab) continue;
            float d = 0.f;
            const ushort* xr = xb + (size_t)j * D;
            for (int q = 0; q < D; ++q)
                d += __uint_as_float(((unsigned)xr[q]) << 16) * xi2[q];
            if (d > pth) {
                S += __expf(fmaf(d, d, fmaf(49.8f, d, -24.99f)));
                ss += d; cnt += 1.f;
            }
        }
        const int lane = tid & 63, wv = tid >> 6;
        S = waveSum(S); ss = waveSum(ss); cnt = waveSum(cnt);
        if (lane == 0) { red[0][wv] = S; red[1][wv] = ss; red[2][wv] = cnt; }
        __syncthreads();
        if (tid == 0) {
            corr[lr_] = red[0][0] + red[0][1] + red[0][2] + red[0][3];
            if (ri == n - 1) {
                lastst[0] = red[1][0] + red[1][1] + red[1][2] + red[1][3];
                lastst[1] = red[2][0] + red[2][1] + red[2][2] + red[2][3];
                lastflag = 1;
            }
        }
        __syncthreads();
    }

    float s;
    if (flag) {
        s = corr[tid];
    } else {
        s = 0.f;
        #pragma unroll
        for (int sl = 0; sl < 8; ++sl) s += part[(size_t)sl * n + i];
    }
    float l = 0.f, nno = 0.f;
    if (s > 0.f)       // has_neg <=> any exp term (each > 0 in fp32)
        l = 0.5f * log1pf(pos_sum[i]) + 0.02f * log1pf(s);
    else
        nno = 1.f;
    const int lane = tid & 63, wv = tid >> 6;
    l = waveSum(l); nno = waveSum(nno);
    __syncthreads();                  // red[] reuse safety
    if (lane == 0) { red[0][wv] = l; red[1][wv] = nno; }
    __syncthreads();
    if (tid == 0) {
        float L = red[0][0] + red[0][1] + red[0][2] + red[0][3];
        float P = red[1][0] + red[1][1] + red[1][2] + red[1][3];
        atomicAdd(&out[0], L / (float)n);
        atomicAdd(&out[1], P / (float)n);
    }
    if (i == n - 1) {                 // block owning the last row writes stats
        out[2] = last4[0] / fmaxf(last4[1], 1.f);
        float a = lastflag ? lastst[0] : last4[2];
        float b2 = lastflag ? lastst[1] : last4[3];
        out[3] = a / fmaxf(b2, 1.f);
    }
}

// ---------------- launch ----------------
extern "C" void kernel_launch(void* const* d_in, const int* in_sizes, int n_in,
                              void* d_out, int out_size, void* d_ws, size_t ws_size,
                              hipStream_t stream) {
    const float* x = (const float*)d_in[0];
    const int*   t = (const int*)d_in[1];
    const int n = in_sizes[1];   // 8192

    float* ws      = (float*)d_ws;
    float* pos_min = ws;                       // [n]
    float* pos_sum = ws + n;                   // [n]
    float* last4   = ws + 2 * n;               // [4]   (zeroed by prep)
    float* part    = ws + 2 * n + 4;           // [8*n] (zeroed by prep)
    int*   offs    = (int*)(ws + 10 * n + 4);             // [NL+1]
    int*   list    = (int*)(ws + 10 * n + 4 + NL + 1);    // [n]
    size_t xb_off  = ((size_t)(11 * n + 4 + NL + 1) + 3) & ~(size_t)3;
    ushort* xb     = (ushort*)(ws + xb_off);              // [n*128] bf16, 16B aligned

    const int total8 = n * D / 8;
    const int nconv = (total8 + 1023) / 1024;
    const int nzero = (8 * n + 4095) / 4096;
    prep_kernel<<<nconv + 1 + nzero, 1024, 0, stream>>>(
        x, xb, total8, t, offs, list, part, last4, (float*)d_out, n, nconv);

    const int nb = n / 128;                    // 64
    const int ntri = nb * (nb + 1) / 2;        // 2080
    fused_kernel<<<POSB + ntri, 256, 0, stream>>>(
        xb, t, offs, list, pos_min, pos_sum, part, last4, n, ntri);

    finalize_kernel<<<n / 256, 256, 0, stream>>>(xb, t, pos_min, pos_sum,
                                                 part, last4, (float*)d_out, n);
}